// Round 10
// baseline (7624.621 us; speedup 1.0000x reference)
//
#include <hip/hip_runtime.h>
#include <math.h>

#define NN 16384
#define SS 2048
#define TT 16
#define RPB 64            // rows per block -> grid 256, 1 block/CU

// np.tanh(f32) mimic: evaluate in f64, round once to f32 (~correctly rounded)
__device__ __forceinline__ float tanh_cr(float a) {
    return (float)tanh((double)a);
}

// direct global->LDS DMA, 16B per lane, dest = uniform base + lane*16
#define GLOAD_LDS(g, l) __builtin_amdgcn_global_load_lds( \
    (const __attribute__((address_space(1))) void*)(g),   \
    (__attribute__((address_space(3))) void*)(l), 16, 0, 0)

// inp[s,t] -> inpT[t,s], f32: tanh(where(u >= 0.01f, u, 0))
__global__ void prep_inp(const float* __restrict__ in, float* __restrict__ inpT) {
    int i = blockIdx.x * blockDim.x + threadIdx.x;
    if (i < SS * TT) {
        int s = i / TT, t = i % TT;
        float v = in[i];
        v = (v >= 0.01f) ? v : 0.0f;
        inpT[t * SS + s] = tanh_cr(v);
    }
}

__global__ void map_init(int* __restrict__ map) {
    int i = blockIdx.x * blockDim.x + threadIdx.x;
    if (i < NN) map[i] = -1;
}

__global__ void map_scatter(const int* __restrict__ idx, int* __restrict__ map) {
    int s = blockIdx.x * blockDim.x + threadIdx.x;
    if (s < SS) map[idx[s]] = s;
}

__device__ __forceinline__ float fold8(float a) {
    a += __shfl_xor(a, 4, 64);
    a += __shfl_xor(a, 1, 64);
    a += __shfl_xor(a, 2, 64);
    return a;
}

// t=0 unchanged (verified R6): 8 lanes/row, stripe j = k mod 8.
__global__ __launch_bounds__(256) void step0(const float* __restrict__ W,
                                             const int* __restrict__ idx,
                                             const float* __restrict__ inp0,
                                             float* __restrict__ x_out,
                                             float* __restrict__ out) {
    int gid = blockIdx.x * blockDim.x + threadIdx.x;
    int row = gid >> 3;
    int j   = gid & 7;
    if (row >= NN) return;
    const float* __restrict__ wrow = W + (size_t)row * NN;
    float acc = 0.0f;
    #pragma unroll 16
    for (int k = j; k < SS; k += 8)
        acc = fmaf(wrow[idx[k]], inp0[k], acc);
    float y = fold8(acc);
    if (j == 0) {
        float v = (y >= 0.01f) ? y : 0.0f;
        v = tanh_cr(5.0f * v);
        x_out[row] = v;
        out[(size_t)row * TT + 0] = v;
    }
}

// t>=1: bit-identical arithmetic to R6 (8 stripes, fold(4,1,2), chunk order).
// Single wave per block, zero barriers. W halves (32KB) DMA'd into a 2-ring
// with XOR-swizzled SOURCE addresses (involution within 64B -> coalescing
// preserved, LDS reads ~conflict-free). Counted vmcnt(32) = one half in
// flight across each compute phase. x staged once per block (same trick).
__global__ __launch_bounds__(64) void step_t(const float* __restrict__ W,
                                             const float* __restrict__ x_in,
                                             const float* __restrict__ inp_t,
                                             const int* __restrict__ map,
                                             float* __restrict__ x_out,
                                             float* __restrict__ out, int t) {
    __shared__ float lx[16384];        // x, sigma7-swizzled      (64 KB)
    __shared__ float lw[2][8192];      // W half-row ring, sigma3 (2x32 KB)
    const int lane = threadIdx.x;      // block = exactly 1 wave
    const int row0 = blockIdx.x * RPB;

    // ---- prologue: stage x, then W(row0, h=0) and W(row0, h=1) ----
    #pragma unroll
    for (int k = 0; k < 64; ++k) {     // x: 4096 granules, sigma7
        int sg = (k << 6) | (lane ^ (k >> 3));            // (k>>3)&7, k<64
        GLOAD_LDS(x_in + (sg << 2), &lx[k << 8]);
    }
    #pragma unroll
    for (int k = 0; k < 32; ++k) {     // W half 0: 2048 granules, sigma3
        int sg = (k << 6) | (lane ^ ((k >> 3) & 3));
        GLOAD_LDS(W + (size_t)row0 * NN + (sg << 2), &lw[0][k << 8]);
    }
    #pragma unroll
    for (int k = 0; k < 32; ++k) {     // W half 1
        int sg = (k << 6) | (lane ^ ((k >> 3) & 3));
        GLOAD_LDS(W + (size_t)row0 * NN + 8192 + (sg << 2), &lw[1][k << 8]);
    }

    const int cl = (lane >> 3) & 3;    // chunk-local (lanes 0..31)
    const int s  = lane & 7;
    const int t2 = s >> 2, u = s & 3;

    // swizzled word offsets, affine in n (i = 4n+q):
    // W: 2048*cl + 4*((2q+t2)^cl) + u + 32n ; X: same with c = 4h+cl
    float y = 0.0f;
    for (int hh = 0; hh < 2 * RPB; ++hh) {
        asm volatile("s_waitcnt vmcnt(32)" ::: "memory");  // half hh landed
        const int row = row0 + (hh >> 1);
        const int h   = hh & 1;
        const float* __restrict__ wb = lw[h];

        float acc = 0.0f;
        if (lane < 32) {
            const int c = (h << 2) | cl;
            const int w0 = (cl << 11) + (((0 + t2) ^ cl) << 2) + u;
            const int w1 = (cl << 11) + (((2 + t2) ^ cl) << 2) + u;
            const int w2 = (cl << 11) + (((4 + t2) ^ cl) << 2) + u;
            const int w3 = (cl << 11) + (((6 + t2) ^ cl) << 2) + u;
            const int x0 = (c  << 11) + (((0 + t2) ^ c) << 2) + u;
            const int x1 = (c  << 11) + (((2 + t2) ^ c) << 2) + u;
            const int x2 = (c  << 11) + (((4 + t2) ^ c) << 2) + u;
            const int x3 = (c  << 11) + (((6 + t2) ^ c) << 2) + u;
            #pragma unroll 8
            for (int n = 0; n < 64; ++n) {     // i = 4n+q, q inner: k ascending
                const int o = n << 5;
                acc = fmaf(wb[w0 + o], lx[x0 + o], acc);
                acc = fmaf(wb[w1 + o], lx[x1 + o], acc);
                acc = fmaf(wb[w2 + o], lx[x2 + o], acc);
                acc = fmaf(wb[w3 + o], lx[x3 + o], acc);
            }
        }
        // fold(4,1,2) within each 8-lane octet (octet cl holds chunk 4h+cl)
        float b = acc + __shfl_xor(acc, 4, 64);
        b += __shfl_xor(b, 1, 64);
        b += __shfl_xor(b, 2, 64);
        // chunk sums accumulated in ascending chunk order (frozen reference)
        if (h == 0) y = 0.0f;
        y += __shfl(b, 0, 64);
        y += __shfl(b, 8, 64);
        y += __shfl(b, 16, 64);
        y += __shfl(b, 24, 64);
        if (h == 1 && lane == 0) {
            int m = map[row];
            float yf = y;
            if (m >= 0) yf += inp_t[m];
            float v = (yf >= 0.01f) ? yf : 0.0f;
            v = tanh_cr(5.0f * v);
            x_out[row] = v;
            out[(size_t)row * TT + t] = v;
        }
        asm volatile("" ::: "memory");         // pin DMA issue after LDS reads
        if (hh + 2 < 2 * RPB) {                // stage half hh+2 into ring[h]
            const int r2 = row0 + ((hh + 2) >> 1);
            const float* wsrc = W + (size_t)r2 * NN + (h << 13);
            float* dst = lw[h];
            #pragma unroll
            for (int k = 0; k < 32; ++k) {
                int sg = (k << 6) | (lane ^ ((k >> 3) & 3));
                GLOAD_LDS(wsrc + (sg << 2), &dst[k << 8]);
            }
        }
    }
}

extern "C" void kernel_launch(void* const* d_in, const int* in_sizes, int n_in,
                              void* d_out, int out_size, void* d_ws, size_t ws_size,
                              hipStream_t stream) {
    const float* W    = (const float*)d_in[0];
    const float* intt = (const float*)d_in[1];
    const int*   idx  = (const int*)d_in[2];
    float* out = (float*)d_out;

    char* ws = (char*)d_ws;
    float* inpT = (float*)ws;                                   // T*S f32 (128 KiB)
    size_t off = (size_t)TT * SS * 4;
    int*   map  = (int*)(ws + off);                             // N ints (64 KiB)
    off += (size_t)NN * 4;
    float* xa   = (float*)(ws + off);                           // N f32 (16B aligned)
    float* xb   = xa + NN;                                      // N f32

    prep_inp<<<(SS * TT + 255) / 256, 256, 0, stream>>>(intt, inpT);
    map_init<<<NN / 256, 256, 0, stream>>>(map);
    map_scatter<<<SS / 256, 256, 0, stream>>>(idx, map);

    step0<<<NN * 8 / 256, 256, 0, stream>>>(W, idx, inpT, xa, out);

    float* xi_ = xa;
    float* xo_ = xb;
    for (int t = 1; t < TT; ++t) {
        step_t<<<NN / RPB, 64, 0, stream>>>(W, xi_, inpT + (size_t)t * SS,
                                            map, xo_, out, t);
        float* tmp = xi_; xi_ = xo_; xo_ = tmp;
    }
}

// Round 11
// 2504.356 us; speedup vs baseline: 3.0445x; 3.0445x over previous
//
#include <hip/hip_runtime.h>
#include <math.h>

#define NN 16384
#define SS 2048
#define TT 16
#define CHUNK 2048

// np.tanh(f32) mimic: evaluate in f64, round once to f32 (~correctly rounded)
__device__ __forceinline__ float tanh_cr(float a) {
    return (float)tanh((double)a);
}

__device__ __forceinline__ float fold8(float a) {
    a += __shfl_xor(a, 4, 64);
    a += __shfl_xor(a, 1, 64);
    a += __shfl_xor(a, 2, 64);
    return a;
}

// inp[s,t] -> inpT[t,s], f32: tanh(where(u >= 0.01f, u, 0))
__global__ void prep_inp(const float* __restrict__ in, float* __restrict__ inpT) {
    int i = blockIdx.x * blockDim.x + threadIdx.x;
    if (i < SS * TT) {
        int s = i / TT, t = i % TT;
        float v = in[i];
        v = (v >= 0.01f) ? v : 0.0f;
        inpT[t * SS + s] = tanh_cr(v);
    }
}

__global__ void map_init(int* __restrict__ map) {
    int i = blockIdx.x * blockDim.x + threadIdx.x;
    if (i < NN) map[i] = -1;
}

__global__ void map_scatter(const int* __restrict__ idx, int* __restrict__ map) {
    int s = blockIdx.x * blockDim.x + threadIdx.x;
    if (s < SS) map[idx[s]] = s;
}

// t=0 (verified R6): 8 lanes/row, stripe j = k mod 8, fold(4,1,2).
__global__ __launch_bounds__(256) void step0(const float* __restrict__ W,
                                             const int* __restrict__ idx,
                                             const float* __restrict__ inp0,
                                             float* __restrict__ x_out,
                                             float* __restrict__ out) {
    int gid = blockIdx.x * blockDim.x + threadIdx.x;
    int row = gid >> 3;
    int j   = gid & 7;
    if (row >= NN) return;
    const float* __restrict__ wrow = W + (size_t)row * NN;
    float acc = 0.0f;
    #pragma unroll 16
    for (int k = j; k < SS; k += 8)
        acc = fmaf(wrow[idx[k]], inp0[k], acc);
    float y = fold8(acc);
    if (j == 0) {
        float v = (y >= 0.01f) ? y : 0.0f;
        v = tanh_cr(5.0f * v);
        x_out[row] = v;
        out[(size_t)row * TT + 0] = v;
    }
}

// ---------- fallback (verified R6 step_t) ----------
__global__ __launch_bounds__(256) void step_t(const float* __restrict__ W,
                                              const float* __restrict__ x_in,
                                              const float* __restrict__ inp_t,
                                              const int* __restrict__ map,
                                              float* __restrict__ x_out,
                                              float* __restrict__ out, int t) {
    int gid = blockIdx.x * blockDim.x + threadIdx.x;
    int row = gid >> 3;
    int j   = gid & 7;
    if (row >= NN) return;
    const float* __restrict__ wrow = W + (size_t)row * NN;
    float y = 0.0f;
    for (int c0 = 0; c0 < NN; c0 += CHUNK) {
        float acc = 0.0f;
        #pragma unroll 16
        for (int k = c0 + j; k < c0 + CHUNK; k += 8)
            acc = fmaf(wrow[k], x_in[k], acc);
        y += fold8(acc);
    }
    if (j == 0) {
        int m = map[row];
        if (m >= 0) y += inp_t[m];
        float v = (y >= 0.01f) ? y : 0.0f;
        v = tanh_cr(5.0f * v);
        x_out[row] = v;
        out[(size_t)row * TT + t] = v;
    }
}

// ---------- fast path ----------

// Wt[k][r] = W[r][k]. 64 k x 256 r tile per block via padded LDS.
__global__ __launch_bounds__(256) void transposeW(const float* __restrict__ W,
                                                  float* __restrict__ Wt) {
    __shared__ float lds[256][65];
    int b  = blockIdx.x;
    int k0 = (b & 255) << 6;     // 256 k-tiles
    int r0 = (b >> 8) << 8;      // 64 r-tiles
    int t  = threadIdx.x;
    #pragma unroll
    for (int it = 0; it < 16; ++it) {
        int idx = (it << 8) + t;           // 0..4095
        int r = idx >> 4, q = idx & 15;    // 16 float4 per row
        float4 v = *reinterpret_cast<const float4*>(
            W + (size_t)(r0 + r) * NN + k0 + (q << 2));
        lds[r][(q << 2) + 0] = v.x;
        lds[r][(q << 2) + 1] = v.y;
        lds[r][(q << 2) + 2] = v.z;
        lds[r][(q << 2) + 3] = v.w;
    }
    __syncthreads();
    #pragma unroll
    for (int it = 0; it < 16; ++it) {
        int idx = (it << 8) + t;
        int kl = idx >> 6, q = idx & 63;   // 64 float4 per k-row
        float4 v;
        v.x = lds[(q << 2) + 0][kl];
        v.y = lds[(q << 2) + 1][kl];
        v.z = lds[(q << 2) + 2][kl];
        v.w = lds[(q << 2) + 3][kl];
        *reinterpret_cast<float4*>(
            Wt + (size_t)(k0 + kl) * NN + r0 + (q << 2)) = v;
    }
}

// Order-preserving per-chunk compaction of nonzero x into 8 stripe sublists.
// Must run with 8 blocks x 256 threads; xl = chunk's 2048 x values in LDS.
__device__ __forceinline__ void build_lists_from_lds(const float* xl, int c,
                                                     float2* __restrict__ klist,
                                                     int* __restrict__ cnt,
                                                     int* wcnt) {
    int tid  = threadIdx.x;
    int lane = tid & 63, w = tid >> 6;
    for (int s = 0; s < 8; ++s) {
        float val = xl[(tid << 3) + s];            // k_local = 8*tid + s
        bool nz = (val != 0.0f);
        unsigned long long mask = __ballot(nz);
        int wp = __popcll(mask & (((unsigned long long)1 << lane) - 1ull));
        int wc = __popcll(mask);
        if (lane == 0) wcnt[w] = wc;
        __syncthreads();
        int off = 0;
        #pragma unroll
        for (int ww = 0; ww < 4; ++ww) if (ww < w) off += wcnt[ww];
        if (nz) {
            int k = (c << 11) + (tid << 3) + s;    // global column index
            klist[(c << 11) + (s << 8) + off + wp] =
                make_float2(__int_as_float(k), val);
        }
        if (tid == 0) cnt[c * 8 + s] = wcnt[0] + wcnt[1] + wcnt[2] + wcnt[3];
        __syncthreads();
    }
}

__global__ __launch_bounds__(256) void build_klists(const float* __restrict__ x,
                                                    float2* __restrict__ klist,
                                                    int* __restrict__ cnt) {
    __shared__ float xl[2048];
    __shared__ int wcnt[4];
    int c = blockIdx.x, tid = threadIdx.x;
    for (int i = tid; i < 2048; i += 256) xl[i] = x[(c << 11) + i];
    __syncthreads();
    build_lists_from_lds(xl, c, klist, cnt, wcnt);
}

// Sparse axpy-form matvec, bit-exact to R6 chains: per (chunk c, stripe s),
// nonzero k ascending updates one sequential fmaf chain; fold + chunk sums
// are combined later in chunk order. Wave = 128 rows (float2/lane).
__global__ __launch_bounds__(256) void axpy_step(const float* __restrict__ Wt,
                                                 const float2* __restrict__ klist,
                                                 const int* __restrict__ cnt,
                                                 float* __restrict__ csum) {
    __shared__ float2 kl_lds[8][256];
    __shared__ int n_lds[8];
    __shared__ float2 pa[4][8][64];
    int b = blockIdx.x;                 // 256 blocks
    int c = b >> 5;                     // chunk 0..7
    int t = threadIdx.x;
    {
        const float2* src = klist + ((size_t)c << 11);
        for (int i = t; i < 2048; i += 256)
            kl_lds[i >> 8][i & 255] = src[i];
        if (t < 8) n_lds[t] = cnt[c * 8 + t];
    }
    __syncthreads();
    int w = t >> 6, lane = t & 63;
    int g  = ((b & 31) << 2) + w;       // row-group 0..127
    int r0 = (g << 7) + (lane << 1);    // this lane's row pair
    const float* __restrict__ wb = Wt + r0;

    for (int s = 0; s < 8; ++s) {
        int n = n_lds[s];
        float a0 = 0.0f, a1 = 0.0f;
        int j = 0;
        for (; j + 8 <= n; j += 8) {
            float2 es[8], wv[8];
            #pragma unroll
            for (int u = 0; u < 8; ++u) es[u] = kl_lds[s][j + u];
            #pragma unroll
            for (int u = 0; u < 8; ++u) {
                int k = __float_as_int(es[u].x);
                wv[u] = *reinterpret_cast<const float2*>(wb + ((size_t)k << 14));
            }
            #pragma unroll
            for (int u = 0; u < 8; ++u) {          // ascending k: frozen order
                a0 = fmaf(wv[u].x, es[u].y, a0);
                a1 = fmaf(wv[u].y, es[u].y, a1);
            }
        }
        for (; j < n; ++j) {
            float2 e = kl_lds[s][j];
            int k = __float_as_int(e.x);
            float2 wv = *reinterpret_cast<const float2*>(wb + ((size_t)k << 14));
            a0 = fmaf(wv.x, e.y, a0);
            a1 = fmaf(wv.y, e.y, a1);
        }
        pa[w][s][lane] = make_float2(a0, a1);
    }
    // fold(4,1,2) == ((b0+b1)+(b2+b3)), b_s = a_s + a_{s+4}  (in-lane, bit-equal)
    float2 v0 = pa[w][0][lane], v1 = pa[w][1][lane], v2 = pa[w][2][lane],
           v3 = pa[w][3][lane], v4 = pa[w][4][lane], v5 = pa[w][5][lane],
           v6 = pa[w][6][lane], v7 = pa[w][7][lane];
    float c0 = ((v0.x + v4.x) + (v1.x + v5.x)) + ((v2.x + v6.x) + (v3.x + v7.x));
    float c1 = ((v0.y + v4.y) + (v1.y + v5.y)) + ((v2.y + v6.y) + (v3.y + v7.y));
    *reinterpret_cast<float2*>(csum + (size_t)c * NN + r0) = make_float2(c0, c1);
}

// y = csum[0..7] in chunk order (+ sensory u), activate, write out,
// then rebuild this chunk's stripe sublists from the fresh x.
__global__ __launch_bounds__(256) void combine_build(const float* __restrict__ csum,
                                                     const float* __restrict__ inp_t,
                                                     const int* __restrict__ map,
                                                     float* __restrict__ x_out,
                                                     float* __restrict__ out, int t,
                                                     float2* __restrict__ klist,
                                                     int* __restrict__ cnt) {
    __shared__ float xl[2048];
    __shared__ int wcnt[4];
    int c = blockIdx.x, tid = threadIdx.x;
    for (int i = 0; i < 8; ++i) {
        int row = (c << 11) + (i << 8) + tid;
        float y = csum[row];
        #pragma unroll
        for (int cc = 1; cc < 8; ++cc) y += csum[(size_t)cc * NN + row];
        int m = map[row];
        if (m >= 0) y += inp_t[m];
        float v = (y >= 0.01f) ? y : 0.0f;
        v = tanh_cr(5.0f * v);
        x_out[row] = v;
        out[((size_t)row << 4) + t] = v;
        xl[(i << 8) + tid] = v;
    }
    __syncthreads();
    build_lists_from_lds(xl, c, klist, cnt, wcnt);
}

extern "C" void kernel_launch(void* const* d_in, const int* in_sizes, int n_in,
                              void* d_out, int out_size, void* d_ws, size_t ws_size,
                              hipStream_t stream) {
    const float* W    = (const float*)d_in[0];
    const float* intt = (const float*)d_in[1];
    const int*   idx  = (const int*)d_in[2];
    float* out = (float*)d_out;

    char* ws = (char*)d_ws;
    float*  inpT  = (float*)(ws + 0);              // 131072 B
    int*    map   = (int*)(ws + 131072);           // 65536 B
    float*  xa    = (float*)(ws + 196608);         // 65536 B
    float*  xb    = (float*)(ws + 262144);         // 65536 B
    float*  csum  = (float*)(ws + 327680);         // 524288 B
    int*    cnt   = (int*)(ws + 851968);           // 256 B
    float2* klist = (float2*)(ws + 852224);        // 131072 B
    float*  Wt    = (float*)(ws + 983296);         // 1 GiB
    const size_t NEED = 983296ull + (size_t)NN * NN * 4ull;

    prep_inp<<<(SS * TT + 255) / 256, 256, 0, stream>>>(intt, inpT);
    map_init<<<NN / 256, 256, 0, stream>>>(map);
    map_scatter<<<SS / 256, 256, 0, stream>>>(idx, map);
    step0<<<NN * 8 / 256, 256, 0, stream>>>(W, idx, inpT, xa, out);

    if (ws_size >= NEED) {
        // fast path: transpose once, then sparse axpy steps (bit-exact order)
        transposeW<<<256 * 64, 256, 0, stream>>>(W, Wt);
        build_klists<<<8, 256, 0, stream>>>(xa, klist, cnt);
        for (int t = 1; t < TT; ++t) {
            axpy_step<<<256, 256, 0, stream>>>(Wt, klist, cnt, csum);
            combine_build<<<8, 256, 0, stream>>>(csum, inpT + (size_t)t * SS,
                                                 map, xa, out, t, klist, cnt);
        }
    } else {
        // fallback: verified R6 dense path
        float* xi_ = xa;
        float* xo_ = xb;
        for (int t = 1; t < TT; ++t) {
            step_t<<<NN * 8 / 256, 256, 0, stream>>>(W, xi_, inpT + (size_t)t * SS,
                                                     map, xo_, out, t);
            float* tmp = xi_; xi_ = xo_; xo_ = tmp;
        }
    }
}